// Round 1
// baseline (125.437 us; speedup 1.0000x reference)
//
#include <hip/hip_runtime.h>
#include <hip/hip_bf16.h>

// Problem constants
#define Bb 4
#define Ll 2048
#define Dd 1024
#define DKk 64
#define BL (Bb*Ll)
#define G_SPLIT 2   // split of the s-range across blocks in attention

typedef __attribute__((ext_vector_type(4))) float f32x4;
typedef __attribute__((ext_vector_type(8))) short bf16x8;

__device__ __forceinline__ unsigned short f2bf(float x) {
  unsigned int u = __builtin_bit_cast(unsigned int, x);
  u += 0x7fffu + ((u >> 16) & 1u);   // RNE
  return (unsigned short)(u >> 16);
}
__device__ __forceinline__ unsigned int pack2bf(float a, float b) {
  return (unsigned int)f2bf(a) | ((unsigned int)f2bf(b) << 16);
}

// ---------------------------------------------------------------------------
// prep: WqT/WkT/WvT [64n][1024k] bf16 ; WoSumT[1024d][64k] bf16 with
// WoSum[k][d] = sum_h Wo[h*64+k][d]  (tile-by-H collapsed into the weight)
// ---------------------------------------------------------------------------
__global__ __launch_bounds__(256)
void prep_kernel(const float* __restrict__ Wq, const float* __restrict__ Wk,
                 const float* __restrict__ Wv, const float* __restrict__ Wo,
                 unsigned short* __restrict__ WqT, unsigned short* __restrict__ WkT,
                 unsigned short* __restrict__ WvT, unsigned short* __restrict__ WoSumT) {
  int idx = blockIdx.x * 256 + threadIdx.x;
  if (idx < 3 * 65536) {
    int which = idx >> 16;
    int r = idx & 65535;
    int n = r & 63, k = r >> 6;                 // consecutive threads -> consecutive n (coalesced read)
    const float* W = which == 0 ? Wq : (which == 1 ? Wk : Wv);
    unsigned short* WT = which == 0 ? WqT : (which == 1 ? WkT : WvT);
    WT[(size_t)n * 1024 + k] = f2bf(W[(size_t)k * 64 + n]);
  } else {
    int r = idx - 3 * 65536;
    int d = r & 1023, k = r >> 10;              // consecutive threads -> consecutive d (coalesced read)
    float s = 0.f;
#pragma unroll
    for (int h = 0; h < 16; ++h) s += Wo[(size_t)(h * 64 + k) * 1024 + d];
    WoSumT[(size_t)d * 64 + k] = f2bf(s);
  }
}

// ---------------------------------------------------------------------------
// proj: X[8192][1024] fp32 @ W[1024][64] -> bf16.
// which = blockIdx.y: 0->Qp, 1->Kp (row major [8192][64]), 2->VpT ([b][64dk][2048s])
// Block: 256 thr (4 waves), 64-row M tile, K-loop BK=64.
// ---------------------------------------------------------------------------
__global__ __launch_bounds__(256)
void proj_kernel(const float* __restrict__ query, const float* __restrict__ key,
                 const float* __restrict__ value,
                 const unsigned short* __restrict__ WqT, const unsigned short* __restrict__ WkT,
                 const unsigned short* __restrict__ WvT,
                 unsigned short* __restrict__ Qp, unsigned short* __restrict__ Kp,
                 unsigned short* __restrict__ VpT) {
  const int which = blockIdx.y;
  const float* X = which == 0 ? query : (which == 1 ? key : value);
  const unsigned short* WT = which == 0 ? WqT : (which == 1 ? WkT : WvT);
  const int R0 = blockIdx.x * 64;

  __shared__ __align__(16) unsigned short Xl[64 * 72];  // +8 pad: 2-way bank alias only
  __shared__ __align__(16) unsigned short Wl[64 * 72];

  const int tid = threadIdx.x;
  const int lane = tid & 63;
  const int w = tid >> 6;
  const int g = lane >> 4, lr = lane & 15;

  f32x4 acc[4];
#pragma unroll
  for (int t = 0; t < 4; ++t) acc[t] = (f32x4){0.f, 0.f, 0.f, 0.f};

  for (int k0 = 0; k0 < 1024; k0 += 64) {
    // stage X tile [64][64] fp32 -> bf16 (1024 float4 chunks)
#pragma unroll
    for (int i = 0; i < 4; ++i) {
      int c = tid + 256 * i;
      int row = c >> 4, cc = c & 15;
      f32x4 v = *(const f32x4*)(X + (size_t)(R0 + row) * 1024 + k0 + cc * 4);
      uint2 pv;
      pv.x = pack2bf(v[0], v[1]);
      pv.y = pack2bf(v[2], v[3]);
      *(uint2*)&Xl[row * 72 + cc * 4] = pv;
    }
    // stage W^T tile [64n][64k] bf16 (512 16B chunks)
#pragma unroll
    for (int i = 0; i < 2; ++i) {
      int c = tid + 256 * i;
      int row = c >> 3, cc = c & 7;
      *(uint4*)&Wl[row * 72 + cc * 8] = *(const uint4*)(WT + (size_t)row * 1024 + k0 + cc * 8);
    }
    __syncthreads();
#pragma unroll
    for (int kh = 0; kh < 2; ++kh) {
      bf16x8 a = *(const bf16x8*)&Xl[(w * 16 + lr) * 72 + kh * 32 + g * 8];
#pragma unroll
      for (int t = 0; t < 4; ++t) {
        bf16x8 b = *(const bf16x8*)&Wl[(t * 16 + lr) * 72 + kh * 32 + g * 8];
        acc[t] = __builtin_amdgcn_mfma_f32_16x16x32_bf16(a, b, acc[t], 0, 0, 0);
      }
    }
    __syncthreads();
  }

  // D layout: row = w*16 + 4g + i, col = 16t + lr
  if (which < 2) {
    unsigned short* P = which == 0 ? Qp : Kp;
#pragma unroll
    for (int t = 0; t < 4; ++t)
#pragma unroll
      for (int i = 0; i < 4; ++i)
        P[(size_t)(R0 + w * 16 + g * 4 + i) * 64 + t * 16 + lr] = f2bf(acc[t][i]);
  } else {
    const int b = R0 >> 11;
    const int sbase = (R0 & 2047) + w * 16 + g * 4;
#pragma unroll
    for (int t = 0; t < 4; ++t) {
      uint2 pv;
      pv.x = pack2bf(acc[t][0], acc[t][1]);
      pv.y = pack2bf(acc[t][2], acc[t][3]);
      *(uint2*)(VpT + (size_t)(b * 64 + t * 16 + lr) * Ll + sbase) = pv;
    }
  }
}

// ---------------------------------------------------------------------------
// attn: flash loop, no-max softmax (scores bounded), swapped QK^T.
// grid (BL/32, G_SPLIT), 128 thr (2 waves of 16 q-rows each).
// Writes partial O^[gy][q][dk] fp32 and l[gy][q].
// ---------------------------------------------------------------------------
__global__ __launch_bounds__(128)
void attn_kernel(const unsigned short* __restrict__ Qp, const unsigned short* __restrict__ Kp,
                 const unsigned short* __restrict__ VpT, const int* __restrict__ mask,
                 float* __restrict__ Opart, float* __restrict__ lpart) {
  const int q0 = blockIdx.x * 32;        // global row base
  const int gy = blockIdx.y;
  const int b = q0 >> 11;
  const int tid = threadIdx.x, lane = tid & 63, w = tid >> 6;
  const int g = lane >> 4, lr = lane & 15;

  __shared__ __align__(16) unsigned short Kl[64 * 72];   // [64 s][64 k] (+pad)
  __shared__ __align__(16) unsigned short Vl[64 * 72];   // [64 dk][64 s] (+pad)

  // Q fragments (B-operand of swapped QK^T): q = q0 + w*16 + lr
  const unsigned short* qrow = Qp + (size_t)(q0 + w * 16 + lr) * 64;
  bf16x8 qf0 = *(const bf16x8*)(qrow + g * 8);
  bf16x8 qf1 = *(const bf16x8*)(qrow + 32 + g * 8);

  f32x4 o[4];
#pragma unroll
  for (int t = 0; t < 4; ++t) o[t] = (f32x4){0.f, 0.f, 0.f, 0.f};
  float lsum = 0.f;

  const int s_begin = gy * (Ll / G_SPLIT);
  const int nTiles = (Ll / G_SPLIT) / 64;
  const int qloc = (q0 & 2047) + w * 16 + lr;
  const int* mbase = mask + ((size_t)b * Ll + qloc) * Ll;

  for (int st = 0; st < nTiles; ++st) {
    const int s0 = s_begin + st * 64;
    // stage K tile (rows b*2048+s0..+63) and V^T tile (dk rows, cols s0..s0+63)
    {
      const unsigned short* ksrc = Kp + (size_t)(b * Ll + s0) * 64;
      const unsigned short* vsrc = VpT + (size_t)b * 64 * Ll + s0;
#pragma unroll
      for (int i = 0; i < 4; ++i) {
        int c = tid + 128 * i;
        int row = c >> 3, cc = c & 7;
        *(uint4*)&Kl[row * 72 + cc * 8] = *(const uint4*)(ksrc + (size_t)row * 64 + cc * 8);
      }
#pragma unroll
      for (int i = 0; i < 4; ++i) {
        int c = tid + 128 * i;
        int row = c >> 3, cc = c & 7;
        *(uint4*)&Vl[row * 72 + cc * 8] = *(const uint4*)(vsrc + (size_t)row * Ll + cc * 8);
      }
    }
    __syncthreads();

    // S^T frags: D[s][q], frag c: s = s0 + 16c + 4g + i, q = lr
    f32x4 sfr[4];
#pragma unroll
    for (int c = 0; c < 4; ++c) {
      f32x4 a4 = (f32x4){0.f, 0.f, 0.f, 0.f};
      bf16x8 a0 = *(const bf16x8*)&Kl[(c * 16 + lr) * 72 + g * 8];
      a4 = __builtin_amdgcn_mfma_f32_16x16x32_bf16(a0, qf0, a4, 0, 0, 0);
      bf16x8 a1 = *(const bf16x8*)&Kl[(c * 16 + lr) * 72 + 32 + g * 8];
      a4 = __builtin_amdgcn_mfma_f32_16x16x32_bf16(a1, qf1, a4, 0, 0, 0);
      sfr[c] = a4;
    }

    // mask + exp (no max needed: scores bounded), pack to bf16
    uint2 packs[4];
#pragma unroll
    for (int c = 0; c < 4; ++c) {
      int4 m = *(const int4*)(mbase + s0 + c * 16 + g * 4);
      float p0 = m.x ? __expf(sfr[c][0] * 0.125f) : 0.f;
      float p1 = m.y ? __expf(sfr[c][1] * 0.125f) : 0.f;
      float p2 = m.z ? __expf(sfr[c][2] * 0.125f) : 0.f;
      float p3 = m.w ? __expf(sfr[c][3] * 0.125f) : 0.f;
      lsum += (p0 + p1) + (p2 + p3);
      packs[c].x = pack2bf(p0, p1);
      packs[c].y = pack2bf(p2, p3);
    }

    // PV: redistribute P^T (D layout) -> B-operand layout via shuffles
#pragma unroll
    for (int h = 0; h < 2; ++h) {
      const int srcLo = lr + ((g & 1) << 5);
      const int srcHi = srcLo + 16;
      uint2 pl0 = packs[2 * h], pl1 = packs[2 * h + 1];
      unsigned a0x = __shfl((int)pl0.x, srcLo), a0y = __shfl((int)pl0.y, srcLo);
      unsigned a1x = __shfl((int)pl1.x, srcLo), a1y = __shfl((int)pl1.y, srcLo);
      unsigned b0x = __shfl((int)pl0.x, srcHi), b0y = __shfl((int)pl0.y, srcHi);
      unsigned b1x = __shfl((int)pl1.x, srcHi), b1y = __shfl((int)pl1.y, srcHi);
      const bool hisel = ((g >> 1) & 1) != 0;
      uint4 bb;
      bb.x = hisel ? a1x : a0x;
      bb.y = hisel ? a1y : a0y;
      bb.z = hisel ? b1x : b0x;
      bb.w = hisel ? b1y : b0y;
      bf16x8 pb = __builtin_bit_cast(bf16x8, bb);
#pragma unroll
      for (int t = 0; t < 4; ++t) {
        bf16x8 av = *(const bf16x8*)&Vl[(t * 16 + lr) * 72 + h * 32 + g * 8];
        o[t] = __builtin_amdgcn_mfma_f32_16x16x32_bf16(av, pb, o[t], 0, 0, 0);
      }
    }
    __syncthreads();
  }

  // reduce l over the 4 lanes holding the same q (lr, lr+16, lr+32, lr+48)
  lsum += __shfl_xor(lsum, 16);
  lsum += __shfl_xor(lsum, 32);

  // store O^T frags: frag t: dk = 16t + 4g + i, q = lr
  float* Ob = Opart + ((size_t)gy * BL + q0 + w * 16 + lr) * 64;
#pragma unroll
  for (int t = 0; t < 4; ++t)
    *(f32x4*)(Ob + t * 16 + g * 4) = o[t];
  if (lane < 16)
    lpart[(size_t)gy * BL + q0 + w * 16 + lane] = lsum;
}

// ---------------------------------------------------------------------------
// oproj: head = (O0+O1)/(l0+l1) -> bf16 ; out = head @ WoSum  (fp32 out)
// grid (128 m-tiles, 4 n-tiles of 256), 256 thr.
// ---------------------------------------------------------------------------
__global__ __launch_bounds__(256)
void oproj_kernel(const float* __restrict__ Opart, const float* __restrict__ lpart,
                  const unsigned short* __restrict__ WoSumT, float* __restrict__ out) {
  const int R0 = blockIdx.x * 64;
  const int n0 = blockIdx.y * 256;
  __shared__ __align__(16) unsigned short Hl[64 * 72];
  __shared__ __align__(16) unsigned short Wl[256 * 72];
  const int tid = threadIdx.x, lane = tid & 63, w = tid >> 6;
  const int g = lane >> 4, lr = lane & 15;

  // combine partials -> head bf16 tile
  {
    int row = tid >> 2, c0 = (tid & 3) * 16;
    int q = R0 + row;
    float inv = 1.f / (lpart[q] + lpart[BL + q]);
    const float* O0 = Opart + (size_t)q * 64;
    const float* O1 = Opart + (size_t)(BL + q) * 64;
#pragma unroll
    for (int j = 0; j < 4; ++j) {
      f32x4 a = *(const f32x4*)(O0 + c0 + j * 4);
      f32x4 c = *(const f32x4*)(O1 + c0 + j * 4);
      uint2 pv;
      pv.x = pack2bf((a[0] + c[0]) * inv, (a[1] + c[1]) * inv);
      pv.y = pack2bf((a[2] + c[2]) * inv, (a[3] + c[3]) * inv);
      *(uint2*)&Hl[row * 72 + c0 + j * 4] = pv;
    }
  }
  // stage WoSumT tile [256 n][64 k]
#pragma unroll
  for (int i = 0; i < 8; ++i) {
    int c = tid + 256 * i;
    int row = c >> 3, cc = c & 7;
    *(uint4*)&Wl[row * 72 + cc * 8] = *(const uint4*)(WoSumT + (size_t)(n0 + row) * 64 + cc * 8);
  }
  __syncthreads();

  f32x4 acc[16];
#pragma unroll
  for (int t = 0; t < 16; ++t) acc[t] = (f32x4){0.f, 0.f, 0.f, 0.f};
#pragma unroll
  for (int kh = 0; kh < 2; ++kh) {
    bf16x8 a = *(const bf16x8*)&Hl[(w * 16 + lr) * 72 + kh * 32 + g * 8];
#pragma unroll
    for (int t = 0; t < 16; ++t) {
      bf16x8 bb = *(const bf16x8*)&Wl[(t * 16 + lr) * 72 + kh * 32 + g * 8];
      acc[t] = __builtin_amdgcn_mfma_f32_16x16x32_bf16(a, bb, acc[t], 0, 0, 0);
    }
  }
  float* ob = out + (size_t)(R0 + w * 16 + g * 4) * 1024 + n0 + lr;
#pragma unroll
  for (int t = 0; t < 16; ++t)
#pragma unroll
    for (int i = 0; i < 4; ++i)
      ob[(size_t)i * 1024 + t * 16] = acc[t][i];
}

// ---------------------------------------------------------------------------
extern "C" void kernel_launch(void* const* d_in, const int* in_sizes, int n_in,
                              void* d_out, int out_size, void* d_ws, size_t ws_size,
                              hipStream_t stream) {
  const float* query = (const float*)d_in[0];
  const float* key   = (const float*)d_in[1];
  const float* value = (const float*)d_in[2];
  const int*   mask  = (const int*)d_in[3];
  const float* Wq    = (const float*)d_in[4];
  const float* Wk    = (const float*)d_in[5];
  const float* Wv    = (const float*)d_in[6];
  const float* Wo    = (const float*)d_in[7];
  float* out = (float*)d_out;

  // workspace carve-up (all 16B aligned)
  unsigned short* Qp   = (unsigned short*)d_ws;           // 8192*64
  unsigned short* Kp   = Qp + (size_t)BL * 64;            // 8192*64
  unsigned short* VpT  = Kp + (size_t)BL * 64;            // 4*64*2048
  unsigned short* WqT  = VpT + (size_t)BL * 64;           // 64*1024
  unsigned short* WkT  = WqT + 65536;
  unsigned short* WvT  = WkT + 65536;
  unsigned short* WoSumT = WvT + 65536;                   // 1024*64
  float* Opart = (float*)(WoSumT + 65536);                // G*8192*64 fp32
  float* lpart = Opart + (size_t)G_SPLIT * BL * 64;       // G*8192

  hipLaunchKernelGGL(prep_kernel, dim3(1024), dim3(256), 0, stream,
                     Wq, Wk, Wv, Wo, WqT, WkT, WvT, WoSumT);
  hipLaunchKernelGGL(proj_kernel, dim3(128, 3), dim3(256), 0, stream,
                     query, key, value, WqT, WkT, WvT, Qp, Kp, VpT);
  hipLaunchKernelGGL(attn_kernel, dim3(BL / 32, G_SPLIT), dim3(128), 0, stream,
                     Qp, Kp, VpT, mask, Opart, lpart);
  hipLaunchKernelGGL(oproj_kernel, dim3(128, 4), dim3(256), 0, stream,
                     Opart, lpart, WoSumT, out);
}

// Round 2
// 105.613 us; speedup vs baseline: 1.1877x; 1.1877x over previous
//
#include <hip/hip_runtime.h>
#include <hip/hip_bf16.h>

// Problem constants
#define Bb 4
#define Ll 2048
#define Dd 1024
#define DKk 64
#define BL (Bb*Ll)
#define G_SPLIT 8   // split of the s-range across blocks in attention

typedef __attribute__((ext_vector_type(4))) float f32x4;
typedef __attribute__((ext_vector_type(8))) short bf16x8;

__device__ __forceinline__ unsigned short f2bf(float x) {
  unsigned int u = __builtin_bit_cast(unsigned int, x);
  u += 0x7fffu + ((u >> 16) & 1u);   // RNE
  return (unsigned short)(u >> 16);
}
__device__ __forceinline__ unsigned int pack2bf(float a, float b) {
  return (unsigned int)f2bf(a) | ((unsigned int)f2bf(b) << 16);
}

// ---------------------------------------------------------------------------
// prep: WqT/WkT/WvT [64n][1024k] bf16 ; WoSumT[1024d][64k] bf16 with
// WoSum[k][d] = sum_h Wo[h*64+k][d]  (tile-by-H collapsed into the weight)
// ---------------------------------------------------------------------------
__global__ __launch_bounds__(256)
void prep_kernel(const float* __restrict__ Wq, const float* __restrict__ Wk,
                 const float* __restrict__ Wv, const float* __restrict__ Wo,
                 unsigned short* __restrict__ WqT, unsigned short* __restrict__ WkT,
                 unsigned short* __restrict__ WvT, unsigned short* __restrict__ WoSumT) {
  int idx = blockIdx.x * 256 + threadIdx.x;
  if (idx < 3 * 65536) {
    int which = idx >> 16;
    int r = idx & 65535;
    int n = r & 63, k = r >> 6;                 // consecutive threads -> consecutive n (coalesced read)
    const float* W = which == 0 ? Wq : (which == 1 ? Wk : Wv);
    unsigned short* WT = which == 0 ? WqT : (which == 1 ? WkT : WvT);
    WT[(size_t)n * 1024 + k] = f2bf(W[(size_t)k * 64 + n]);
  } else {
    int r = idx - 3 * 65536;
    int d = r & 1023, k = r >> 10;              // consecutive threads -> consecutive d (coalesced read)
    float s = 0.f;
#pragma unroll
    for (int h = 0; h < 16; ++h) s += Wo[(size_t)(h * 64 + k) * 1024 + d];
    WoSumT[(size_t)d * 64 + k] = f2bf(s);
  }
}

// ---------------------------------------------------------------------------
// proj: X[8192][1024] fp32 @ W[1024][64] -> bf16.
// which = blockIdx.y: 0->Qp, 1->Kp (row major [8192][64]), 2->VpT ([b][64dk][2048s])
// Block: 256 thr (4 waves), 64-row M tile, K-loop BK=64.
// ---------------------------------------------------------------------------
__global__ __launch_bounds__(256)
void proj_kernel(const float* __restrict__ query, const float* __restrict__ key,
                 const float* __restrict__ value,
                 const unsigned short* __restrict__ WqT, const unsigned short* __restrict__ WkT,
                 const unsigned short* __restrict__ WvT,
                 unsigned short* __restrict__ Qp, unsigned short* __restrict__ Kp,
                 unsigned short* __restrict__ VpT) {
  const int which = blockIdx.y;
  const float* X = which == 0 ? query : (which == 1 ? key : value);
  const unsigned short* WT = which == 0 ? WqT : (which == 1 ? WkT : WvT);
  const int R0 = blockIdx.x * 64;

  __shared__ __align__(16) unsigned short Xl[64 * 72];  // +8 pad: 2-way bank alias only
  __shared__ __align__(16) unsigned short Wl[64 * 72];

  const int tid = threadIdx.x;
  const int lane = tid & 63;
  const int w = tid >> 6;
  const int g = lane >> 4, lr = lane & 15;

  f32x4 acc[4];
#pragma unroll
  for (int t = 0; t < 4; ++t) acc[t] = (f32x4){0.f, 0.f, 0.f, 0.f};

  for (int k0 = 0; k0 < 1024; k0 += 64) {
    // stage X tile [64][64] fp32 -> bf16 (1024 float4 chunks)
#pragma unroll
    for (int i = 0; i < 4; ++i) {
      int c = tid + 256 * i;
      int row = c >> 4, cc = c & 15;
      f32x4 v = *(const f32x4*)(X + (size_t)(R0 + row) * 1024 + k0 + cc * 4);
      uint2 pv;
      pv.x = pack2bf(v[0], v[1]);
      pv.y = pack2bf(v[2], v[3]);
      *(uint2*)&Xl[row * 72 + cc * 4] = pv;
    }
    // stage W^T tile [64n][64k] bf16 (512 16B chunks)
#pragma unroll
    for (int i = 0; i < 2; ++i) {
      int c = tid + 256 * i;
      int row = c >> 3, cc = c & 7;
      *(uint4*)&Wl[row * 72 + cc * 8] = *(const uint4*)(WT + (size_t)row * 1024 + k0 + cc * 8);
    }
    __syncthreads();
#pragma unroll
    for (int kh = 0; kh < 2; ++kh) {
      bf16x8 a = *(const bf16x8*)&Xl[(w * 16 + lr) * 72 + kh * 32 + g * 8];
#pragma unroll
      for (int t = 0; t < 4; ++t) {
        bf16x8 b = *(const bf16x8*)&Wl[(t * 16 + lr) * 72 + kh * 32 + g * 8];
        acc[t] = __builtin_amdgcn_mfma_f32_16x16x32_bf16(a, b, acc[t], 0, 0, 0);
      }
    }
    __syncthreads();
  }

  // D layout: row = w*16 + 4g + i, col = 16t + lr
  if (which < 2) {
    unsigned short* P = which == 0 ? Qp : Kp;
#pragma unroll
    for (int t = 0; t < 4; ++t)
#pragma unroll
      for (int i = 0; i < 4; ++i)
        P[(size_t)(R0 + w * 16 + g * 4 + i) * 64 + t * 16 + lr] = f2bf(acc[t][i]);
  } else {
    const int b = R0 >> 11;
    const int sbase = (R0 & 2047) + w * 16 + g * 4;
#pragma unroll
    for (int t = 0; t < 4; ++t) {
      uint2 pv;
      pv.x = pack2bf(acc[t][0], acc[t][1]);
      pv.y = pack2bf(acc[t][2], acc[t][3]);
      *(uint2*)(VpT + (size_t)(b * 64 + t * 16 + lr) * Ll + sbase) = pv;
    }
  }
}

// ---------------------------------------------------------------------------
// attn v2: no LDS, no barriers. K/V fragments read directly from global
// (L2-resident: K+V = 2 MB total). 2 waves/block, 16 q-rows per wave.
// grid (BL/32, G_SPLIT) = (256, 8) = 2048 blocks -> 16 waves/CU.
// No-max softmax (scores bounded by input scale), swapped QK^T.
// ---------------------------------------------------------------------------
__global__ __launch_bounds__(128, 4)
void attn_kernel(const unsigned short* __restrict__ Qp, const unsigned short* __restrict__ Kp,
                 const unsigned short* __restrict__ VpT, const int* __restrict__ mask,
                 float* __restrict__ Opart, float* __restrict__ lpart) {
  const int q0 = blockIdx.x * 32;        // global row base
  const int gy = blockIdx.y;
  const int b = q0 >> 11;
  const int tid = threadIdx.x, lane = tid & 63, w = tid >> 6;
  const int g = lane >> 4, lr = lane & 15;

  // Q fragments (B-operand of swapped QK^T): q = q0 + w*16 + lr
  const unsigned short* qrow = Qp + (size_t)(q0 + w * 16 + lr) * 64;
  bf16x8 qf0 = *(const bf16x8*)(qrow + g * 8);
  bf16x8 qf1 = *(const bf16x8*)(qrow + 32 + g * 8);

  f32x4 o[4];
#pragma unroll
  for (int t = 0; t < 4; ++t) o[t] = (f32x4){0.f, 0.f, 0.f, 0.f};
  float lsum = 0.f;

  const int qloc = (q0 & 2047) + w * 16 + lr;
  const int* mbase = mask + ((size_t)b * Ll + qloc) * Ll;
  const unsigned short* Kb = Kp + (size_t)b * Ll * 64;
  const unsigned short* Vb = VpT + (size_t)b * 64 * Ll;

  const int s_begin = gy * (Ll / G_SPLIT);
#pragma unroll
  for (int st = 0; st < (Ll / G_SPLIT) / 64; ++st) {
    const int s0 = s_begin + st * 64;

    // load K fragments + mask for this 64-s tile
    bf16x8 kf0[4], kf1[4];
    int4 mm[4];
#pragma unroll
    for (int c = 0; c < 4; ++c) {
      const unsigned short* kr = Kb + (size_t)(s0 + c * 16 + lr) * 64;
      kf0[c] = *(const bf16x8*)(kr + g * 8);
      kf1[c] = *(const bf16x8*)(kr + 32 + g * 8);
      mm[c] = *(const int4*)(mbase + s0 + c * 16 + g * 4);
    }

    // S^T frags: D[s][q], frag c: s = s0 + 16c + 4g + i, q = lr
    // then mask + exp (no max needed: scores bounded), pack to bf16
    uint2 packs[4];
#pragma unroll
    for (int c = 0; c < 4; ++c) {
      f32x4 a4 = (f32x4){0.f, 0.f, 0.f, 0.f};
      a4 = __builtin_amdgcn_mfma_f32_16x16x32_bf16(kf0[c], qf0, a4, 0, 0, 0);
      a4 = __builtin_amdgcn_mfma_f32_16x16x32_bf16(kf1[c], qf1, a4, 0, 0, 0);
      float p0 = mm[c].x ? __expf(a4[0] * 0.125f) : 0.f;
      float p1 = mm[c].y ? __expf(a4[1] * 0.125f) : 0.f;
      float p2 = mm[c].z ? __expf(a4[2] * 0.125f) : 0.f;
      float p3 = mm[c].w ? __expf(a4[3] * 0.125f) : 0.f;
      lsum += (p0 + p1) + (p2 + p3);
      packs[c].x = pack2bf(p0, p1);
      packs[c].y = pack2bf(p2, p3);
    }

    // PV: redistribute P^T (D layout) -> B-operand layout via shuffles,
    // V fragments straight from global (L2-resident)
#pragma unroll
    for (int h = 0; h < 2; ++h) {
      const int srcLo = lr + ((g & 1) << 5);
      const int srcHi = srcLo + 16;
      uint2 pl0 = packs[2 * h], pl1 = packs[2 * h + 1];
      unsigned a0x = __shfl((int)pl0.x, srcLo), a0y = __shfl((int)pl0.y, srcLo);
      unsigned a1x = __shfl((int)pl1.x, srcLo), a1y = __shfl((int)pl1.y, srcLo);
      unsigned b0x = __shfl((int)pl0.x, srcHi), b0y = __shfl((int)pl0.y, srcHi);
      unsigned b1x = __shfl((int)pl1.x, srcHi), b1y = __shfl((int)pl1.y, srcHi);
      const bool hisel = ((g >> 1) & 1) != 0;
      uint4 bb;
      bb.x = hisel ? a1x : a0x;
      bb.y = hisel ? a1y : a0y;
      bb.z = hisel ? b1x : b0x;
      bb.w = hisel ? b1y : b0y;
      bf16x8 pb = __builtin_bit_cast(bf16x8, bb);
#pragma unroll
      for (int t = 0; t < 4; ++t) {
        bf16x8 av = *(const bf16x8*)(Vb + (size_t)(t * 16 + lr) * Ll + s0 + h * 32 + g * 8);
        o[t] = __builtin_amdgcn_mfma_f32_16x16x32_bf16(av, pb, o[t], 0, 0, 0);
      }
    }
  }

  // reduce l over the 4 lanes holding the same q (lr, lr+16, lr+32, lr+48)
  lsum += __shfl_xor(lsum, 16);
  lsum += __shfl_xor(lsum, 32);

  // store O^T frags: frag t: dk = 16t + 4g + i, q = lr
  float* Ob = Opart + ((size_t)gy * BL + q0 + w * 16 + lr) * 64;
#pragma unroll
  for (int t = 0; t < 4; ++t)
    *(f32x4*)(Ob + t * 16 + g * 4) = o[t];
  if (lane < 16)
    lpart[(size_t)gy * BL + q0 + w * 16 + lane] = lsum;
}

// ---------------------------------------------------------------------------
// oproj: head = (sum_g O_g)/(sum_g l_g) -> bf16 ; out = head @ WoSum (fp32 out)
// grid (128 m-tiles, 4 n-tiles of 256), 256 thr.
// ---------------------------------------------------------------------------
__global__ __launch_bounds__(256)
void oproj_kernel(const float* __restrict__ Opart, const float* __restrict__ lpart,
                  const unsigned short* __restrict__ WoSumT, float* __restrict__ out) {
  const int R0 = blockIdx.x * 64;
  const int n0 = blockIdx.y * 256;
  __shared__ __align__(16) unsigned short Hl[64 * 72];
  __shared__ __align__(16) unsigned short Wl[256 * 72];
  const int tid = threadIdx.x, lane = tid & 63, w = tid >> 6;
  const int g = lane >> 4, lr = lane & 15;

  // combine partials -> head bf16 tile
  {
    int row = tid >> 2, c0 = (tid & 3) * 16;
    int q = R0 + row;
    float l = 0.f;
#pragma unroll
    for (int gg = 0; gg < G_SPLIT; ++gg) l += lpart[(size_t)gg * BL + q];
    float inv = 1.f / l;
#pragma unroll
    for (int j = 0; j < 4; ++j) {
      f32x4 s = (f32x4){0.f, 0.f, 0.f, 0.f};
#pragma unroll
      for (int gg = 0; gg < G_SPLIT; ++gg) {
        f32x4 a = *(const f32x4*)(Opart + ((size_t)gg * BL + q) * 64 + c0 + j * 4);
        s[0] += a[0]; s[1] += a[1]; s[2] += a[2]; s[3] += a[3];
      }
      uint2 pv;
      pv.x = pack2bf(s[0] * inv, s[1] * inv);
      pv.y = pack2bf(s[2] * inv, s[3] * inv);
      *(uint2*)&Hl[row * 72 + c0 + j * 4] = pv;
    }
  }
  // stage WoSumT tile [256 n][64 k]
#pragma unroll
  for (int i = 0; i < 8; ++i) {
    int c = tid + 256 * i;
    int row = c >> 3, cc = c & 7;
    *(uint4*)&Wl[row * 72 + cc * 8] = *(const uint4*)(WoSumT + (size_t)(n0 + row) * 64 + cc * 8);
  }
  __syncthreads();

  f32x4 acc[16];
#pragma unroll
  for (int t = 0; t < 16; ++t) acc[t] = (f32x4){0.f, 0.f, 0.f, 0.f};
#pragma unroll
  for (int kh = 0; kh < 2; ++kh) {
    bf16x8 a = *(const bf16x8*)&Hl[(w * 16 + lr) * 72 + kh * 32 + g * 8];
#pragma unroll
    for (int t = 0; t < 16; ++t) {
      bf16x8 bb = *(const bf16x8*)&Wl[(t * 16 + lr) * 72 + kh * 32 + g * 8];
      acc[t] = __builtin_amdgcn_mfma_f32_16x16x32_bf16(a, bb, acc[t], 0, 0, 0);
    }
  }
  float* ob = out + (size_t)(R0 + w * 16 + g * 4) * 1024 + n0 + lr;
#pragma unroll
  for (int t = 0; t < 16; ++t)
#pragma unroll
    for (int i = 0; i < 4; ++i)
      ob[(size_t)i * 1024 + t * 16] = acc[t][i];
}

// ---------------------------------------------------------------------------
extern "C" void kernel_launch(void* const* d_in, const int* in_sizes, int n_in,
                              void* d_out, int out_size, void* d_ws, size_t ws_size,
                              hipStream_t stream) {
  const float* query = (const float*)d_in[0];
  const float* key   = (const float*)d_in[1];
  const float* value = (const float*)d_in[2];
  const int*   mask  = (const int*)d_in[3];
  const float* Wq    = (const float*)d_in[4];
  const float* Wk    = (const float*)d_in[5];
  const float* Wv    = (const float*)d_in[6];
  const float* Wo    = (const float*)d_in[7];
  float* out = (float*)d_out;

  // workspace carve-up (all 16B aligned)
  unsigned short* Qp   = (unsigned short*)d_ws;           // 8192*64
  unsigned short* Kp   = Qp + (size_t)BL * 64;            // 8192*64
  unsigned short* VpT  = Kp + (size_t)BL * 64;            // 4*64*2048
  unsigned short* WqT  = VpT + (size_t)BL * 64;           // 64*1024
  unsigned short* WkT  = WqT + 65536;
  unsigned short* WvT  = WkT + 65536;
  unsigned short* WoSumT = WvT + 65536;                   // 1024*64
  float* Opart = (float*)(WoSumT + 65536);                // G*8192*64 fp32
  float* lpart = Opart + (size_t)G_SPLIT * BL * 64;       // G*8192

  hipLaunchKernelGGL(prep_kernel, dim3(1024), dim3(256), 0, stream,
                     Wq, Wk, Wv, Wo, WqT, WkT, WvT, WoSumT);
  hipLaunchKernelGGL(proj_kernel, dim3(128, 3), dim3(256), 0, stream,
                     query, key, value, WqT, WkT, WvT, Qp, Kp, VpT);
  hipLaunchKernelGGL(attn_kernel, dim3(BL / 32, G_SPLIT), dim3(128), 0, stream,
                     Qp, Kp, VpT, mask, Opart, lpart);
  hipLaunchKernelGGL(oproj_kernel, dim3(128, 4), dim3(256), 0, stream,
                     Opart, lpart, WoSumT, out);
}